// Round 3
// baseline (234.081 us; speedup 1.0000x reference)
//
#include <hip/hip_runtime.h>

typedef __attribute__((ext_vector_type(4))) float f32x4;
typedef __attribute__((ext_vector_type(8))) short s16x8;
typedef __attribute__((ext_vector_type(4))) unsigned short u16x4;

__device__ inline unsigned short f2bf(float f) {
  unsigned int u = __builtin_bit_cast(unsigned int, f);
  u += 0x7fff + ((u >> 16) & 1);   // RTNE
  return (unsigned short)(u >> 16);
}
__device__ inline float bf2f(unsigned short u) {
  return __builtin_bit_cast(float, (unsigned int)u << 16);
}

// ---------------- K0: cast / transpose (vectorized) ----------------
__global__ __launch_bounds__(256) void cast_kernel(
    const float* __restrict__ v, const float* __restrict__ k, const float* __restrict__ q,
    const float* __restrict__ wq, const float* __restrict__ wk, const float* __restrict__ wv,
    const float* __restrict__ wo, const float* __restrict__ pos,
    unsigned short* __restrict__ qbf, unsigned short* __restrict__ kbf,
    unsigned short* __restrict__ vbf, unsigned short* __restrict__ wqT,
    unsigned short* __restrict__ wkT, unsigned short* __restrict__ wvT,
    unsigned short* __restrict__ woT, unsigned short* __restrict__ ebf) {
  int seg = blockIdx.y;
  int tid = blockIdx.x * blockDim.x + threadIdx.x;   // gridDim.x=256 -> 65536 threads
  int stride = gridDim.x * blockDim.x;
  if (seg < 3) {
    const float* src = seg == 0 ? q : (seg == 1 ? k : v);
    unsigned short* dst = seg == 0 ? qbf : (seg == 1 ? kbf : vbf);
    for (int i = tid; i < 4096 * 512 / 4; i += stride) {
      f32x4 x = *(const f32x4*)&src[i * 4];
      u16x4 o = {f2bf(x[0]), f2bf(x[1]), f2bf(x[2]), f2bf(x[3])};
      *(u16x4*)&dst[i * 4] = o;
    }
  } else if (seg < 7) {
    const float* src = seg == 3 ? wq : seg == 4 ? wk : seg == 5 ? wv : wo;
    unsigned short* dst = seg == 3 ? wqT : seg == 4 ? wkT : seg == 5 ? wvT : woT;
    for (int i = tid; i < 512 * 128; i += stride) {  // quads along k
      int n = i >> 7, k0 = (i & 127) * 4;
      u16x4 o = {f2bf(src[(k0 + 0) * 512 + n]), f2bf(src[(k0 + 1) * 512 + n]),
                 f2bf(src[(k0 + 2) * 512 + n]), f2bf(src[(k0 + 3) * 512 + n])};
      *(u16x4*)&dst[n * 512 + k0] = o;
    }
  } else {
    for (int i = tid; i < 1024 * 64 / 4; i += stride) {
      f32x4 x = *(const f32x4*)&pos[1024 * 64 + i * 4];
      u16x4 o = {f2bf(x[0]), f2bf(x[1]), f2bf(x[2]), f2bf(x[3])};
      *(u16x4*)&ebf[i * 4] = o;
    }
  }
}

// ---------------- shared GEMM mainloop (128x128, K=512) ----------------
__device__ __forceinline__ void gemm_main(
    const unsigned short* __restrict__ A, const unsigned short* __restrict__ Bt,
    unsigned short* As, unsigned short* Bs, int r0, int c0, int tid,
    f32x4 acc[4][4]) {
  int lane = tid & 63, w = tid >> 6;
  int wr = w >> 1, wc = w & 1;
  int frow = lane & 15, kg = lane >> 4;
  for (int k0 = 0; k0 < 512; k0 += 32) {
#pragma unroll
    for (int j = 0; j < 2; ++j) {
      int t = tid + j * 256;
      int row = t >> 2, col = (t & 3) * 8;
      *(s16x8*)&As[row * 32 + col] = *(const s16x8*)&A[(size_t)(r0 + row) * 512 + k0 + col];
      *(s16x8*)&Bs[row * 32 + col] = *(const s16x8*)&Bt[(size_t)(c0 + row) * 512 + k0 + col];
    }
    __syncthreads();
    s16x8 af[4], bfr[4];
#pragma unroll
    for (int mi = 0; mi < 4; ++mi) af[mi] = *(s16x8*)&As[(wr * 64 + mi * 16 + frow) * 32 + kg * 8];
#pragma unroll
    for (int ni = 0; ni < 4; ++ni) bfr[ni] = *(s16x8*)&Bs[(wc * 64 + ni * 16 + frow) * 32 + kg * 8];
#pragma unroll
    for (int mi = 0; mi < 4; ++mi)
#pragma unroll
      for (int ni = 0; ni < 4; ++ni)
        acc[mi][ni] = __builtin_amdgcn_mfma_f32_16x16x32_bf16(af[mi], bfr[ni], acc[mi][ni], 0, 0, 0);
    __syncthreads();
  }
}

// ---------------- K1: fused q/k/v projections (z = 0,1,2) ----------------
__global__ __launch_bounds__(256, 2) void proj3_kernel(
    const unsigned short* __restrict__ qbf, const unsigned short* __restrict__ kbf,
    const unsigned short* __restrict__ vbf, const unsigned short* __restrict__ wqT,
    const unsigned short* __restrict__ wkT, const unsigned short* __restrict__ wvT,
    const float* __restrict__ wq_b, const float* __restrict__ wk_b,
    const float* __restrict__ wv_b, unsigned short* __restrict__ qhw,
    unsigned short* __restrict__ khw, unsigned short* __restrict__ vhT) {
  __shared__ unsigned short As[128 * 32];
  __shared__ unsigned short Bs[128 * 32];
  int z = blockIdx.z;
  const unsigned short* A = z == 0 ? qbf : z == 1 ? kbf : vbf;
  const unsigned short* Bt = z == 0 ? wqT : z == 1 ? wkT : wvT;
  const float* bias = z == 0 ? wq_b : z == 1 ? wk_b : wv_b;
  unsigned short* outp = z == 0 ? qhw : z == 1 ? khw : vhT;
  int r0 = blockIdx.x * 128, c0 = blockIdx.y * 128;
  int tid = threadIdx.x;
  int lane = tid & 63, w = tid >> 6;
  int wr = w >> 1, wc = w & 1;
  int frow = lane & 15, kg = lane >> 4;
  f32x4 acc[4][4] = {};
  gemm_main(A, Bt, As, Bs, r0, c0, tid, acc);
#pragma unroll
  for (int ni = 0; ni < 4; ++ni) {
    int gc = c0 + wc * 64 + ni * 16 + frow;
    float bi = bias[gc];
#pragma unroll
    for (int mi = 0; mi < 4; ++mi) {
#pragma unroll
      for (int reg = 0; reg < 4; ++reg) {
        int gr = r0 + wr * 64 + mi * 16 + kg * 4 + reg;
        float val = acc[mi][ni][reg] + bi;
        if (z != 2) {   // [nh][l][d]
          outp[(size_t)((gr >> 10) * 8 + (gc >> 6)) * 65536 +
               (size_t)(gr & 1023) * 64 + (gc & 63)] = f2bf(val);
        } else {        // vh transposed: [nh][d][l]
          outp[(size_t)((gr >> 10) * 8 + (gc >> 6)) * 65536 +
               (size_t)(gc & 63) * 1024 + (gr & 1023)] = f2bf(val);
        }
      }
    }
  }
}

// ---------------- K3: final output GEMM (fp32 out) ----------------
__global__ __launch_bounds__(256, 2) void gemm_out_kernel(
    const unsigned short* __restrict__ A, const unsigned short* __restrict__ Bt,
    const float* __restrict__ bias, float* __restrict__ outp) {
  __shared__ unsigned short As[128 * 32];
  __shared__ unsigned short Bs[128 * 32];
  int r0 = blockIdx.x * 128, c0 = blockIdx.y * 128;
  int tid = threadIdx.x;
  int lane = tid & 63, w = tid >> 6;
  int wr = w >> 1, wc = w & 1;
  int frow = lane & 15, kg = lane >> 4;
  f32x4 acc[4][4] = {};
  gemm_main(A, Bt, As, Bs, r0, c0, tid, acc);
#pragma unroll
  for (int ni = 0; ni < 4; ++ni) {
    int gc = c0 + wc * 64 + ni * 16 + frow;
    float bi = bias[gc];
#pragma unroll
    for (int mi = 0; mi < 4; ++mi)
#pragma unroll
      for (int reg = 0; reg < 4; ++reg) {
        int gr = r0 + wr * 64 + mi * 16 + kg * 4 + reg;
        outp[(size_t)gr * 512 + gc] = acc[mi][ni][reg] + bi;
      }
  }
}

// ---------------- K2: fused relative attention ----------------
// Per block: one (nh), 16 query rows, 256 threads (4 waves), 33 KB LDS.
// __launch_bounds__(256,3): VGPR budget 170 -> no spill (R1's (256,4) clamped
// to 64 VGPR and spilled lg[16], +360 MB scratch traffic). LDS allows 4
// blocks/CU; VGPR ~112-160 gives 3-4 blocks/CU.
// S (bf16 [16][1024], XOR-swizzled): holds qe in phases A/B, normalized P in phase D.
__global__ __launch_bounds__(256, 3) void attn_kernel(
    const unsigned short* __restrict__ qh, const unsigned short* __restrict__ kh,
    const unsigned short* __restrict__ vhT, const unsigned short* __restrict__ ebf,
    const float* __restrict__ mask, float* __restrict__ attn_out,
    unsigned short* __restrict__ ctx) {
  __shared__ unsigned short S[16 * 1024];      // 32 KB
  __shared__ float redmax[4][16], redsum[4][16];
  int nh = blockIdx.y;
  int l0 = blockIdx.x * 16;
  int tid = threadIdx.x;
  int lane = tid & 63, w = tid >> 6;
  int frow = lane & 15, kg = lane >> 4;

  auto sp = [&](int r, int c) -> unsigned short* {
    int byte = (r << 11) + (c << 1);
    byte ^= (r & 7) << 4;
    return (unsigned short*)((char*)S + byte);
  };

  // Q fragments (row = frow, k = kg*8 + j, two K-halves)
  const unsigned short* qbase = qh + ((size_t)nh * 1024 + l0 + frow) * 64 + kg * 8;
  s16x8 qf0 = *(const s16x8*)(qbase);
  s16x8 qf1 = *(const s16x8*)(qbase + 32);

  // ---- Phase A: qe = Qh @ E^T (only tiles whose columns are ever gathered) ----
  int cmin = 1008 - l0;   // gather needs c >= 1023-(l0+15)
  for (int t = 0; t < 16; ++t) {
    int j0 = w * 256 + t * 16;
    if (j0 + 15 < cmin) continue;            // wave-uniform skip
    const unsigned short* eb = ebf + (size_t)(j0 + frow) * 64 + kg * 8;
    s16x8 b0 = *(const s16x8*)(eb);
    s16x8 b1 = *(const s16x8*)(eb + 32);
    f32x4 a = {};
    a = __builtin_amdgcn_mfma_f32_16x16x32_bf16(qf0, b0, a, 0, 0, 0);
    a = __builtin_amdgcn_mfma_f32_16x16x32_bf16(qf1, b1, a, 0, 0, 0);
#pragma unroll
    for (int reg = 0; reg < 4; ++reg) *sp(kg * 4 + reg, j0 + frow) = f2bf(a[reg]);
  }
  __syncthreads();

  // ---- Phase B: QK^T into registers ----
  f32x4 lg[16];
  for (int t = 0; t < 16; ++t) {
    int m0 = w * 256 + t * 16;
    const unsigned short* kb = kh + ((size_t)nh * 1024 + m0 + frow) * 64 + kg * 8;
    s16x8 b0 = *(const s16x8*)(kb);
    s16x8 b1 = *(const s16x8*)(kb + 32);
    f32x4 a = {};
    a = __builtin_amdgcn_mfma_f32_16x16x32_bf16(qf0, b0, a, 0, 0, 0);
    a = __builtin_amdgcn_mfma_f32_16x16x32_bf16(qf1, b1, a, 0, 0, 0);
    lg[t] = a;
  }
  // srel gather + scale + mask
  for (int t = 0; t < 16; ++t) {
    int m = w * 256 + t * 16 + frow;
#pragma unroll
    for (int reg = 0; reg < 4; ++reg) {
      int r = kg * 4 + reg;
      int lq = l0 + r;
      float srel = (m <= lq) ? bf2f(*sp(r, 1023 + m - lq)) : 0.f;
      lg[t][reg] = (lg[t][reg] + srel) * 0.125f + mask[(size_t)lq * 1024 + m] * -1e9f;
    }
  }

  // ---- softmax: wave-local partials in registers ----
  float wm[4], wsum[4];
#pragma unroll
  for (int reg = 0; reg < 4; ++reg) {
    float mx = lg[0][reg];
#pragma unroll
    for (int t = 1; t < 16; ++t) mx = fmaxf(mx, lg[t][reg]);
#pragma unroll
    for (int d = 1; d < 16; d <<= 1) mx = fmaxf(mx, __shfl_xor(mx, d));
    wm[reg] = mx;
    float s = 0.f;
#pragma unroll
    for (int t = 0; t < 16; ++t) {
      lg[t][reg] = __expf(lg[t][reg] - mx);
      s += lg[t][reg];
    }
#pragma unroll
    for (int d = 1; d < 16; d <<= 1) s += __shfl_xor(s, d);
    wsum[reg] = s;
  }
  if (frow == 0) {
#pragma unroll
    for (int reg = 0; reg < 4; ++reg) {
      redmax[w][kg * 4 + reg] = wm[reg];
      redsum[w][kg * 4 + reg] = wsum[reg];
    }
  }
  __syncthreads();   // stats ready AND all srel reads of S complete

  float fac[4];
#pragma unroll
  for (int reg = 0; reg < 4; ++reg) {
    int r = kg * 4 + reg;
    float gmax = fmaxf(fmaxf(redmax[0][r], redmax[1][r]), fmaxf(redmax[2][r], redmax[3][r]));
    float gsum = redsum[0][r] * __expf(redmax[0][r] - gmax) +
                 redsum[1][r] * __expf(redmax[1][r] - gmax) +
                 redsum[2][r] * __expf(redmax[2][r] - gmax) +
                 redsum[3][r] * __expf(redmax[3][r] - gmax);
    fac[reg] = __expf(wm[reg] - gmax) / gsum;
  }

  // write normalized attn to global + P (bf16) into S
  size_t abase = ((size_t)nh * 1024 + l0) * 1024;
  for (int t = 0; t < 16; ++t) {
    int m = w * 256 + t * 16 + frow;
#pragma unroll
    for (int reg = 0; reg < 4; ++reg) {
      int r = kg * 4 + reg;
      float pn = lg[t][reg] * fac[reg];
      attn_out[abase + (size_t)r * 1024 + m] = pn;
      *sp(r, m) = f2bf(pn);
    }
  }
  __syncthreads();

  // ---- Phase D: ctx = P @ V (P already normalized, bf16 in S) ----
  {
    int d0 = w * 16;
    const unsigned short* vb = vhT + ((size_t)nh * 64 + d0 + frow) * 1024;
    f32x4 acc = {};
    for (int ks = 0; ks < 32; ++ks) {
      int kk = ks * 32 + kg * 8;
      s16x8 a = *(s16x8*)sp(frow, kk);          // 16B-aligned swizzled b128
      s16x8 b = *(const s16x8*)(vb + kk);
      acc = __builtin_amdgcn_mfma_f32_16x16x32_bf16(a, b, acc, 0, 0, 0);
    }
    int n = nh >> 3, h = nh & 7;
#pragma unroll
    for (int reg = 0; reg < 4; ++reg) {
      int rr = kg * 4 + reg;
      ctx[((size_t)(n * 1024 + l0 + rr)) * 512 + h * 64 + d0 + frow] = f2bf(acc[reg]);
    }
  }
}

extern "C" void kernel_launch(void* const* d_in, const int* in_sizes, int n_in,
                              void* d_out, int out_size, void* d_ws, size_t ws_size,
                              hipStream_t stream) {
  const float* v = (const float*)d_in[0];
  const float* k = (const float*)d_in[1];
  const float* q = (const float*)d_in[2];
  const float* mask = (const float*)d_in[3];
  const float* wq_w = (const float*)d_in[4];
  const float* wq_b = (const float*)d_in[5];
  const float* wk_w = (const float*)d_in[6];
  const float* wk_b = (const float*)d_in[7];
  const float* wv_w = (const float*)d_in[8];
  const float* wv_b = (const float*)d_in[9];
  const float* wo_w = (const float*)d_in[10];
  const float* wo_b = (const float*)d_in[11];
  const float* pos = (const float*)d_in[12];

  float* outp = (float*)d_out;
  float* attn_out = outp + (size_t)4 * 1024 * 512;

  char* ws = (char*)d_ws;
  unsigned short* qbf = (unsigned short*)(ws);                              // 4 MB (reused as ctx)
  unsigned short* kbf = (unsigned short*)(ws + ((size_t)4 << 20));          // 4 MB
  unsigned short* vbf = (unsigned short*)(ws + ((size_t)8 << 20));          // 4 MB
  unsigned short* wqT = (unsigned short*)(ws + ((size_t)12 << 20));         // 512 KB
  unsigned short* wkT = (unsigned short*)(ws + ((size_t)12 << 20) + (512 << 10));
  unsigned short* wvT = (unsigned short*)(ws + ((size_t)13 << 20));
  unsigned short* woT = (unsigned short*)(ws + ((size_t)13 << 20) + (512 << 10));
  unsigned short* ebf = (unsigned short*)(ws + ((size_t)14 << 20));         // 128 KB
  unsigned short* qhw = (unsigned short*)(ws + ((size_t)16 << 20));         // 4 MB
  unsigned short* khw = (unsigned short*)(ws + ((size_t)20 << 20));         // 4 MB
  unsigned short* vhT = (unsigned short*)(ws + ((size_t)24 << 20));         // 4 MB
  unsigned short* ctx = qbf;  // qbf dead after projections

  cast_kernel<<<dim3(256, 8), 256, 0, stream>>>(v, k, q, wq_w, wk_w, wv_w, wo_w, pos,
                                                qbf, kbf, vbf, wqT, wkT, wvT, woT, ebf);
  proj3_kernel<<<dim3(32, 4, 3), 256, 0, stream>>>(qbf, kbf, vbf, wqT, wkT, wvT,
                                                   wq_b, wk_b, wv_b, qhw, khw, vhT);
  attn_kernel<<<dim3(64, 32), 256, 0, stream>>>(qhw, khw, vhT, ebf, mask, attn_out, ctx);
  gemm_out_kernel<<<dim3(32, 4), 256, 0, stream>>>(ctx, woT, wo_b, outp);
}

// Round 4
// 166.246 us; speedup vs baseline: 1.4080x; 1.4080x over previous
//
#include <hip/hip_runtime.h>

typedef __attribute__((ext_vector_type(4))) float f32x4;
typedef __attribute__((ext_vector_type(8))) short s16x8;
typedef __attribute__((ext_vector_type(4))) unsigned short u16x4;

__device__ inline unsigned short f2bf(float f) {
  unsigned int u = __builtin_bit_cast(unsigned int, f);
  u += 0x7fff + ((u >> 16) & 1);   // RTNE
  return (unsigned short)(u >> 16);
}
__device__ inline float bf2f(unsigned short u) {
  return __builtin_bit_cast(float, (unsigned int)u << 16);
}

// ---------------- K0: cast / transpose (vectorized) ----------------
__global__ __launch_bounds__(256) void cast_kernel(
    const float* __restrict__ v, const float* __restrict__ k, const float* __restrict__ q,
    const float* __restrict__ wq, const float* __restrict__ wk, const float* __restrict__ wv,
    const float* __restrict__ wo, const float* __restrict__ pos,
    unsigned short* __restrict__ qbf, unsigned short* __restrict__ kbf,
    unsigned short* __restrict__ vbf, unsigned short* __restrict__ wqT,
    unsigned short* __restrict__ wkT, unsigned short* __restrict__ wvT,
    unsigned short* __restrict__ woT, unsigned short* __restrict__ ebf) {
  int seg = blockIdx.y;
  int tid = blockIdx.x * blockDim.x + threadIdx.x;   // gridDim.x=256 -> 65536 threads
  int stride = gridDim.x * blockDim.x;
  if (seg < 3) {
    const float* src = seg == 0 ? q : (seg == 1 ? k : v);
    unsigned short* dst = seg == 0 ? qbf : (seg == 1 ? kbf : vbf);
    for (int i = tid; i < 4096 * 512 / 4; i += stride) {
      f32x4 x = *(const f32x4*)&src[i * 4];
      u16x4 o = {f2bf(x[0]), f2bf(x[1]), f2bf(x[2]), f2bf(x[3])};
      *(u16x4*)&dst[i * 4] = o;
    }
  } else if (seg < 7) {
    const float* src = seg == 3 ? wq : seg == 4 ? wk : seg == 5 ? wv : wo;
    unsigned short* dst = seg == 3 ? wqT : seg == 4 ? wkT : seg == 5 ? wvT : woT;
    for (int i = tid; i < 512 * 128; i += stride) {  // quads along k
      int n = i >> 7, k0 = (i & 127) * 4;
      u16x4 o = {f2bf(src[(k0 + 0) * 512 + n]), f2bf(src[(k0 + 1) * 512 + n]),
                 f2bf(src[(k0 + 2) * 512 + n]), f2bf(src[(k0 + 3) * 512 + n])};
      *(u16x4*)&dst[n * 512 + k0] = o;
    }
  } else {
    for (int i = tid; i < 1024 * 64 / 4; i += stride) {
      f32x4 x = *(const f32x4*)&pos[1024 * 64 + i * 4];
      u16x4 o = {f2bf(x[0]), f2bf(x[1]), f2bf(x[2]), f2bf(x[3])};
      *(u16x4*)&ebf[i * 4] = o;
    }
  }
}

// ---------------- shared GEMM mainloop (128x128, K=512) ----------------
__device__ __forceinline__ void gemm_main(
    const unsigned short* __restrict__ A, const unsigned short* __restrict__ Bt,
    unsigned short* As, unsigned short* Bs, int r0, int c0, int tid,
    f32x4 acc[4][4]) {
  int lane = tid & 63, w = tid >> 6;
  int wr = w >> 1, wc = w & 1;
  int frow = lane & 15, kg = lane >> 4;
  for (int k0 = 0; k0 < 512; k0 += 32) {
#pragma unroll
    for (int j = 0; j < 2; ++j) {
      int t = tid + j * 256;
      int row = t >> 2, col = (t & 3) * 8;
      *(s16x8*)&As[row * 32 + col] = *(const s16x8*)&A[(size_t)(r0 + row) * 512 + k0 + col];
      *(s16x8*)&Bs[row * 32 + col] = *(const s16x8*)&Bt[(size_t)(c0 + row) * 512 + k0 + col];
    }
    __syncthreads();
    s16x8 af[4], bfr[4];
#pragma unroll
    for (int mi = 0; mi < 4; ++mi) af[mi] = *(s16x8*)&As[(wr * 64 + mi * 16 + frow) * 32 + kg * 8];
#pragma unroll
    for (int ni = 0; ni < 4; ++ni) bfr[ni] = *(s16x8*)&Bs[(wc * 64 + ni * 16 + frow) * 32 + kg * 8];
#pragma unroll
    for (int mi = 0; mi < 4; ++mi)
#pragma unroll
      for (int ni = 0; ni < 4; ++ni)
        acc[mi][ni] = __builtin_amdgcn_mfma_f32_16x16x32_bf16(af[mi], bfr[ni], acc[mi][ni], 0, 0, 0);
    __syncthreads();
  }
}

// ---------------- K1: fused q/k/v projections (z = 0,1,2) ----------------
__global__ __launch_bounds__(256, 2) void proj3_kernel(
    const unsigned short* __restrict__ qbf, const unsigned short* __restrict__ kbf,
    const unsigned short* __restrict__ vbf, const unsigned short* __restrict__ wqT,
    const unsigned short* __restrict__ wkT, const unsigned short* __restrict__ wvT,
    const float* __restrict__ wq_b, const float* __restrict__ wk_b,
    const float* __restrict__ wv_b, unsigned short* __restrict__ qhw,
    unsigned short* __restrict__ khw, unsigned short* __restrict__ vhT) {
  __shared__ unsigned short As[128 * 32];
  __shared__ unsigned short Bs[128 * 32];
  int z = blockIdx.z;
  const unsigned short* A = z == 0 ? qbf : z == 1 ? kbf : vbf;
  const unsigned short* Bt = z == 0 ? wqT : z == 1 ? wkT : wvT;
  const float* bias = z == 0 ? wq_b : z == 1 ? wk_b : wv_b;
  unsigned short* outp = z == 0 ? qhw : z == 1 ? khw : vhT;
  int r0 = blockIdx.x * 128, c0 = blockIdx.y * 128;
  int tid = threadIdx.x;
  int lane = tid & 63, w = tid >> 6;
  int wr = w >> 1, wc = w & 1;
  int frow = lane & 15, kg = lane >> 4;
  f32x4 acc[4][4] = {};
  gemm_main(A, Bt, As, Bs, r0, c0, tid, acc);
#pragma unroll
  for (int ni = 0; ni < 4; ++ni) {
    int gc = c0 + wc * 64 + ni * 16 + frow;
    float bi = bias[gc];
#pragma unroll
    for (int mi = 0; mi < 4; ++mi) {
#pragma unroll
      for (int reg = 0; reg < 4; ++reg) {
        int gr = r0 + wr * 64 + mi * 16 + kg * 4 + reg;
        float val = acc[mi][ni][reg] + bi;
        if (z != 2) {   // [nh][l][d]
          outp[(size_t)((gr >> 10) * 8 + (gc >> 6)) * 65536 +
               (size_t)(gr & 1023) * 64 + (gc & 63)] = f2bf(val);
        } else {        // vh transposed: [nh][d][l]
          outp[(size_t)((gr >> 10) * 8 + (gc >> 6)) * 65536 +
               (size_t)(gc & 63) * 1024 + (gr & 1023)] = f2bf(val);
        }
      }
    }
  }
}

// ---------------- K3: final output GEMM (fp32 out) ----------------
__global__ __launch_bounds__(256, 2) void gemm_out_kernel(
    const unsigned short* __restrict__ A, const unsigned short* __restrict__ Bt,
    const float* __restrict__ bias, float* __restrict__ outp) {
  __shared__ unsigned short As[128 * 32];
  __shared__ unsigned short Bs[128 * 32];
  int r0 = blockIdx.x * 128, c0 = blockIdx.y * 128;
  int tid = threadIdx.x;
  int lane = tid & 63, w = tid >> 6;
  int wr = w >> 1, wc = w & 1;
  int frow = lane & 15, kg = lane >> 4;
  f32x4 acc[4][4] = {};
  gemm_main(A, Bt, As, Bs, r0, c0, tid, acc);
#pragma unroll
  for (int ni = 0; ni < 4; ++ni) {
    int gc = c0 + wc * 64 + ni * 16 + frow;
    float bi = bias[gc];
#pragma unroll
    for (int mi = 0; mi < 4; ++mi)
#pragma unroll
      for (int reg = 0; reg < 4; ++reg) {
        int gr = r0 + wr * 64 + mi * 16 + kg * 4 + reg;
        outp[(size_t)gr * 512 + gc] = acc[mi][ni][reg] + bi;
      }
  }
}

// ---------------- K2: fused relative attention ----------------
// Per block: one (nh), 16 query rows, 256 threads (4 waves), 33 KB LDS.
// __launch_bounds__(256,2): no VGPR clamp (R1's (256,4)->64 VGPR and R2's
// (256,3)->84 VGPR both spilled lg[16] to scratch: +70 MB fetch / +140 MB
// write). All lg-touching loops are #pragma unroll so indexing is static
// (rule: runtime-indexed ext_vector arrays go to scratch).
// S (bf16 [16][1024], XOR-swizzled): holds qe in phases A/B, normalized P in D.
__global__ __launch_bounds__(256, 2) void attn_kernel(
    const unsigned short* __restrict__ qh, const unsigned short* __restrict__ kh,
    const unsigned short* __restrict__ vhT, const unsigned short* __restrict__ ebf,
    const float* __restrict__ mask, float* __restrict__ attn_out,
    unsigned short* __restrict__ ctx) {
  __shared__ unsigned short S[16 * 1024];      // 32 KB
  __shared__ float redmax[4][16], redsum[4][16];
  int nh = blockIdx.y;
  int l0 = blockIdx.x * 16;
  int tid = threadIdx.x;
  int lane = tid & 63, w = tid >> 6;
  int frow = lane & 15, kg = lane >> 4;

  auto sp = [&](int r, int c) -> unsigned short* {
    int byte = (r << 11) + (c << 1);
    byte ^= (r & 7) << 4;
    return (unsigned short*)((char*)S + byte);
  };

  // Q fragments (row = frow, k = kg*8 + j, two K-halves)
  const unsigned short* qbase = qh + ((size_t)nh * 1024 + l0 + frow) * 64 + kg * 8;
  s16x8 qf0 = *(const s16x8*)(qbase);
  s16x8 qf1 = *(const s16x8*)(qbase + 32);

  // ---- Phase A: qe = Qh @ E^T (only tiles whose columns are ever gathered) ----
  int cmin = 1008 - l0;   // gather needs c >= 1023-(l0+15)
#pragma unroll
  for (int t = 0; t < 16; ++t) {
    int j0 = w * 256 + t * 16;
    if (j0 + 15 < cmin) continue;            // wave-uniform skip
    const unsigned short* eb = ebf + (size_t)(j0 + frow) * 64 + kg * 8;
    s16x8 b0 = *(const s16x8*)(eb);
    s16x8 b1 = *(const s16x8*)(eb + 32);
    f32x4 a = {};
    a = __builtin_amdgcn_mfma_f32_16x16x32_bf16(qf0, b0, a, 0, 0, 0);
    a = __builtin_amdgcn_mfma_f32_16x16x32_bf16(qf1, b1, a, 0, 0, 0);
#pragma unroll
    for (int reg = 0; reg < 4; ++reg) *sp(kg * 4 + reg, j0 + frow) = f2bf(a[reg]);
  }
  __syncthreads();

  // ---- Phase B: QK^T into registers ----
  f32x4 lg[16];
#pragma unroll
  for (int t = 0; t < 16; ++t) {
    int m0 = w * 256 + t * 16;
    const unsigned short* kb = kh + ((size_t)nh * 1024 + m0 + frow) * 64 + kg * 8;
    s16x8 b0 = *(const s16x8*)(kb);
    s16x8 b1 = *(const s16x8*)(kb + 32);
    f32x4 a = {};
    a = __builtin_amdgcn_mfma_f32_16x16x32_bf16(qf0, b0, a, 0, 0, 0);
    a = __builtin_amdgcn_mfma_f32_16x16x32_bf16(qf1, b1, a, 0, 0, 0);
    lg[t] = a;
  }
  // srel gather + scale + mask
#pragma unroll
  for (int t = 0; t < 16; ++t) {
    int m = w * 256 + t * 16 + frow;
#pragma unroll
    for (int reg = 0; reg < 4; ++reg) {
      int r = kg * 4 + reg;
      int lq = l0 + r;
      float srel = (m <= lq) ? bf2f(*sp(r, 1023 + m - lq)) : 0.f;
      lg[t][reg] = (lg[t][reg] + srel) * 0.125f + mask[(size_t)lq * 1024 + m] * -1e9f;
    }
  }

  // ---- softmax: wave-local partials in registers ----
  float wm[4], wsum[4];
#pragma unroll
  for (int reg = 0; reg < 4; ++reg) {
    float mx = lg[0][reg];
#pragma unroll
    for (int t = 1; t < 16; ++t) mx = fmaxf(mx, lg[t][reg]);
#pragma unroll
    for (int d = 1; d < 16; d <<= 1) mx = fmaxf(mx, __shfl_xor(mx, d));
    wm[reg] = mx;
    float s = 0.f;
#pragma unroll
    for (int t = 0; t < 16; ++t) {
      lg[t][reg] = __expf(lg[t][reg] - mx);
      s += lg[t][reg];
    }
#pragma unroll
    for (int d = 1; d < 16; d <<= 1) s += __shfl_xor(s, d);
    wsum[reg] = s;
  }
  if (frow == 0) {
#pragma unroll
    for (int reg = 0; reg < 4; ++reg) {
      redmax[w][kg * 4 + reg] = wm[reg];
      redsum[w][kg * 4 + reg] = wsum[reg];
    }
  }
  __syncthreads();   // stats ready AND all srel reads of S complete

  float fac[4];
#pragma unroll
  for (int reg = 0; reg < 4; ++reg) {
    int r = kg * 4 + reg;
    float gmax = fmaxf(fmaxf(redmax[0][r], redmax[1][r]), fmaxf(redmax[2][r], redmax[3][r]));
    float gsum = redsum[0][r] * __expf(redmax[0][r] - gmax) +
                 redsum[1][r] * __expf(redmax[1][r] - gmax) +
                 redsum[2][r] * __expf(redmax[2][r] - gmax) +
                 redsum[3][r] * __expf(redmax[3][r] - gmax);
    fac[reg] = __expf(wm[reg] - gmax) / gsum;
  }

  // write normalized attn to global + P (bf16) into S
  size_t abase = ((size_t)nh * 1024 + l0) * 1024;
#pragma unroll
  for (int t = 0; t < 16; ++t) {
    int m = w * 256 + t * 16 + frow;
#pragma unroll
    for (int reg = 0; reg < 4; ++reg) {
      int r = kg * 4 + reg;
      float pn = lg[t][reg] * fac[reg];
      attn_out[abase + (size_t)r * 1024 + m] = pn;
      *sp(r, m) = f2bf(pn);
    }
  }
  __syncthreads();

  // ---- Phase D: ctx = P @ V (P already normalized, bf16 in S) ----
  {
    int d0 = w * 16;
    const unsigned short* vb = vhT + ((size_t)nh * 64 + d0 + frow) * 1024;
    f32x4 acc = {};
#pragma unroll
    for (int ks = 0; ks < 32; ++ks) {
      int kk = ks * 32 + kg * 8;
      s16x8 a = *(s16x8*)sp(frow, kk);          // 16B-aligned swizzled b128
      s16x8 b = *(const s16x8*)(vb + kk);
      acc = __builtin_amdgcn_mfma_f32_16x16x32_bf16(a, b, acc, 0, 0, 0);
    }
    int n = nh >> 3, h = nh & 7;
#pragma unroll
    for (int reg = 0; reg < 4; ++reg) {
      int rr = kg * 4 + reg;
      ctx[((size_t)(n * 1024 + l0 + rr)) * 512 + h * 64 + d0 + frow] = f2bf(acc[reg]);
    }
  }
}

extern "C" void kernel_launch(void* const* d_in, const int* in_sizes, int n_in,
                              void* d_out, int out_size, void* d_ws, size_t ws_size,
                              hipStream_t stream) {
  const float* v = (const float*)d_in[0];
  const float* k = (const float*)d_in[1];
  const float* q = (const float*)d_in[2];
  const float* mask = (const float*)d_in[3];
  const float* wq_w = (const float*)d_in[4];
  const float* wq_b = (const float*)d_in[5];
  const float* wk_w = (const float*)d_in[6];
  const float* wk_b = (const float*)d_in[7];
  const float* wv_w = (const float*)d_in[8];
  const float* wv_b = (const float*)d_in[9];
  const float* wo_w = (const float*)d_in[10];
  const float* wo_b = (const float*)d_in[11];
  const float* pos = (const float*)d_in[12];

  float* outp = (float*)d_out;
  float* attn_out = outp + (size_t)4 * 1024 * 512;

  char* ws = (char*)d_ws;
  unsigned short* qbf = (unsigned short*)(ws);                              // 4 MB (reused as ctx)
  unsigned short* kbf = (unsigned short*)(ws + ((size_t)4 << 20));          // 4 MB
  unsigned short* vbf = (unsigned short*)(ws + ((size_t)8 << 20));          // 4 MB
  unsigned short* wqT = (unsigned short*)(ws + ((size_t)12 << 20));         // 512 KB
  unsigned short* wkT = (unsigned short*)(ws + ((size_t)12 << 20) + (512 << 10));
  unsigned short* wvT = (unsigned short*)(ws + ((size_t)13 << 20));
  unsigned short* woT = (unsigned short*)(ws + ((size_t)13 << 20) + (512 << 10));
  unsigned short* ebf = (unsigned short*)(ws + ((size_t)14 << 20));         // 128 KB
  unsigned short* qhw = (unsigned short*)(ws + ((size_t)16 << 20));         // 4 MB
  unsigned short* khw = (unsigned short*)(ws + ((size_t)20 << 20));         // 4 MB
  unsigned short* vhT = (unsigned short*)(ws + ((size_t)24 << 20));         // 4 MB
  unsigned short* ctx = qbf;  // qbf dead after projections

  cast_kernel<<<dim3(256, 8), 256, 0, stream>>>(v, k, q, wq_w, wk_w, wv_w, wo_w, pos,
                                                qbf, kbf, vbf, wqT, wkT, wvT, woT, ebf);
  proj3_kernel<<<dim3(32, 4, 3), 256, 0, stream>>>(qbf, kbf, vbf, wqT, wkT, wvT,
                                                   wq_b, wk_b, wv_b, qhw, khw, vhT);
  attn_kernel<<<dim3(64, 32), 256, 0, stream>>>(qhw, khw, vhT, ebf, mask, attn_out, ctx);
  gemm_out_kernel<<<dim3(32, 4), 256, 0, stream>>>(ctx, woT, wo_b, outp);
}